// Round 11
// baseline (80.946 us; speedup 1.0000x reference)
//
#include <hip/hip_runtime.h>
#include <hip/hip_bf16.h>
#include <math.h>

#define Bn 128
#define Tn 512
#define Cn 256
#define Hn 64
#define NQKV 192        // 3*H fused output columns
#define XP 264          // padded bf16 LDS stride for GEMM tiles
#define HP2 72          // padded bf16 LDS stride for attn tiles (144 B)
#define SCL 0.18033688011112042f   // log2(e)/8 : exp2-domain softmax scale

typedef __attribute__((ext_vector_type(8))) short short8v;   // 8 bf16
typedef __attribute__((ext_vector_type(4))) float float4v;   // MFMA C/D

__device__ __forceinline__ ushort f2bf(float f) {
    __hip_bfloat16 h = __float2bfloat16(f);   // RNE
    return *reinterpret_cast<ushort*>(&h);
}
__device__ __forceinline__ unsigned int bfpair(float lo, float hi) {
    return (unsigned int)f2bf(lo) | ((unsigned int)f2bf(hi) << 16);
}
__device__ __forceinline__ short8v pk8(float4 a, float4 b) {
    short8v r;
    r[0] = (short)f2bf(a.x); r[1] = (short)f2bf(a.y);
    r[2] = (short)f2bf(a.z); r[3] = (short)f2bf(a.w);
    r[4] = (short)f2bf(b.x); r[5] = (short)f2bf(b.y);
    r[6] = (short)f2bf(b.z); r[7] = (short)f2bf(b.w);
    return r;
}

// ---------------------------------------------------------------------------
// Prep: WcT[m*64+h][c] = W_m[c][h] as bf16 (row-major [col][k]).
// ---------------------------------------------------------------------------
__global__ __launch_bounds__(256) void prep_w_kernel(
    const float* __restrict__ Wq, const float* __restrict__ Wk,
    const float* __restrict__ Wv, ushort* __restrict__ wcT)
{
    const int row = blockIdx.x;          // 0..191
    const int c   = threadIdx.x;         // 0..255
    const float* W = (row < 64) ? Wq : (row < 128) ? Wk : Wv;
    const int h = row & 63;
    wcT[row * Cn + c] = f2bf(W[c * Hn + h]);
}

// ---------------------------------------------------------------------------
// QKV GEMM — r10 structure, templated for ablation.
// STORE=1: full kernel (q,k fp32 dword; vT bf16 ushort4 transposed).
// STORE=0: identical staging + MFMA, accumulators kept live via asm
//          (rule #17: DCE-proof ablation), ZERO global stores.
// ---------------------------------------------------------------------------
template<int STORE>
__global__ __launch_bounds__(256) void qkv_mfma_kernel(
    const float* __restrict__ x, const ushort* __restrict__ wcT,
    float* __restrict__ q, float* __restrict__ k, ushort* __restrict__ vT)
{
    __shared__ ushort xs[64 * XP];
    __shared__ ushort wsh[NQKV * XP];
    const int tid = threadIdx.x;
    const long row0 = (long)blockIdx.x * 64;

    // stage WcT: 192*256 bf16 = 6144 uint4, 24/thread, coalesced
    {
        const uint4* w16 = (const uint4*)wcT;
        #pragma unroll
        for (int i = 0; i < 24; ++i) {
            int idx = tid + i * 256;
            int r   = idx >> 5;
            int c8  = idx & 31;
            *(uint4*)&wsh[r * XP + c8 * 8] = w16[idx];
        }
    }
    // stage x tile 64x256 fp32 -> bf16: 4096 float4, 16/thread, coalesced
    {
        const float4* x4 = (const float4*)(x + row0 * Cn);
        #pragma unroll
        for (int i = 0; i < 16; ++i) {
            int idx = tid + i * 256;
            int r   = idx >> 6;
            int c4  = idx & 63;
            float4 f = x4[idx];
            union { ushort u[4]; uint2 p; } pk;
            pk.u[0] = f2bf(f.x); pk.u[1] = f2bf(f.y);
            pk.u[2] = f2bf(f.z); pk.u[3] = f2bf(f.w);
            *(uint2*)&xs[r * XP + c4 * 4] = pk.p;
        }
    }
    __syncthreads();

    const int lane = tid & 63;
    const int wv   = tid >> 6;
    const int lr   = lane & 15;
    const int hi   = lane >> 4;

    const ushort* arow = &xs[(wv * 16 + lr) * XP + hi * 8];
    const ushort* brow = &wsh[lr * XP + hi * 8];

    float4v acc[12];
    #pragma unroll
    for (int n = 0; n < 12; ++n) acc[n] = (float4v){0.f, 0.f, 0.f, 0.f};

    #pragma unroll
    for (int ks = 0; ks < 8; ++ks) {
        short8v a = *(const short8v*)(arow + ks * 32);
        #pragma unroll
        for (int n = 0; n < 12; ++n) {
            short8v b = *(const short8v*)(brow + (n * 16) * XP + ks * 32);
            acc[n] = __builtin_amdgcn_mfma_f32_16x16x32_bf16(a, b, acc[n], 0, 0, 0);
        }
    }

    if (STORE) {
        // q,k: fp32 scalar dword stores
        const long grow0 = row0 + wv * 16 + hi * 4;
        #pragma unroll
        for (int n = 0; n < 8; ++n) {
            int col = n * 16 + lr;
            float* outp = (col < 64) ? q : k;
            int hcol = col & 63;
            #pragma unroll
            for (int reg = 0; reg < 4; ++reg)
                outp[(grow0 + reg) * Hn + hcol] = acc[n][reg];
        }
        // V: transposed bf16, one ushort4 (8 B) store per n-frag
        const int bb   = (int)(row0 >> 9);
        const int tloc = (int)(grow0 & 511);
        #pragma unroll
        for (int n = 8; n < 12; ++n) {
            int h = (n - 8) * 16 + lr;
            ushort4 pk;
            pk.x = f2bf(acc[n][0]); pk.y = f2bf(acc[n][1]);
            pk.z = f2bf(acc[n][2]); pk.w = f2bf(acc[n][3]);
            *(ushort4*)(vT + ((long)bb * Hn + h) * Tn + tloc) = pk;
        }
    } else {
        // ablation: keep every accumulator live, no memory traffic
        #pragma unroll
        for (int n = 0; n < 12; ++n)
            asm volatile("" :: "v"(acc[n][0]), "v"(acc[n][1]),
                              "v"(acc[n][2]), "v"(acc[n][3]));
    }
}

// ---------------------------------------------------------------------------
// MFMA flash attention, 128-row Q tile, 8 waves (512 thr). Unchanged (r10).
// ---------------------------------------------------------------------------
__global__ __launch_bounds__(512) void attn_mfma_kernel(
    const float* __restrict__ q32, const float* __restrict__ k32,
    const ushort* __restrict__ vT, float* __restrict__ out)
{
    __shared__ ushort Ks[64 * HP2];        // [key s][h]
    __shared__ ushort Vt[64 * HP2];        // [h][key s]
    __shared__ ushort Pl[8][16 * HP2];     // per-wave P rows

    const int tid = threadIdx.x;
    const int f   = blockIdx.x;            // 0..511
    const int c   = f & 255;
    const int b   = c >> 1;
    const int par = c & 1;
    const int qtp = (f < 256) ? par : (3 - par);   // q-tile 0..3
    const int ntiles = 2 * qtp + 2;

    const long base  = (long)b * Tn * Hn;
    const int lane = tid & 63;
    const int wv   = tid >> 6;             // 0..7
    const int lr   = lane & 15;
    const int hi   = lane >> 4;

    const int qrow_g = qtp * 128 + wv * 16;
    const int mrow0  = qrow_g + hi * 4;

    short8v qa[2];
    {
        const float* qp = q32 + base + (long)(qrow_g + lr) * Hn + hi * 8;
        float4 a0 = *(const float4*)(qp);
        float4 a1 = *(const float4*)(qp + 4);
        float4 a2 = *(const float4*)(qp + 32);
        float4 a3 = *(const float4*)(qp + 36);
        qa[0] = pk8(a0, a1);
        qa[1] = pk8(a2, a3);
    }

    const int sr  = tid >> 3;
    const int sc8 = tid & 7;
    float4 kf0 = *(const float4*)(k32 + base + (long)sr * Hn + sc8 * 8);
    float4 kf1 = *(const float4*)(k32 + base + (long)sr * Hn + sc8 * 8 + 4);
    uint4 vreg = *(const uint4*)(vT + base + (long)sr * Tn + sc8 * 8);

    float4v o[4];
    #pragma unroll
    for (int n = 0; n < 4; ++n) o[n] = (float4v){0.f, 0.f, 0.f, 0.f};
    float m[4], l[4];
    #pragma unroll
    for (int reg = 0; reg < 4; ++reg) { m[reg] = -INFINITY; l[reg] = 0.f; }

    for (int kt = 0; kt < ntiles; ++kt) {
        __syncthreads();
        {
            uint4 kp;
            kp.x = bfpair(kf0.x, kf0.y); kp.y = bfpair(kf0.z, kf0.w);
            kp.z = bfpair(kf1.x, kf1.y); kp.w = bfpair(kf1.z, kf1.w);
            *(uint4*)&Ks[sr * HP2 + sc8 * 8] = kp;
            *(uint4*)&Vt[sr * HP2 + sc8 * 8] = vreg;
        }
        __syncthreads();
        if (kt + 1 < ntiles) {
            const float* kp2 = k32 + base + (long)((kt + 1) * 64 + sr) * Hn + sc8 * 8;
            kf0  = *(const float4*)(kp2);
            kf1  = *(const float4*)(kp2 + 4);
            vreg = *(const uint4*)(vT + base + (long)sr * Tn + (kt + 1) * 64 + sc8 * 8);
        }
        if (kt * 64 > qrow_g + 15) continue;

        float4v s4[4];
        #pragma unroll
        for (int n = 0; n < 4; ++n) s4[n] = (float4v){0.f, 0.f, 0.f, 0.f};
        #pragma unroll
        for (int ks = 0; ks < 2; ++ks) {
            short8v a = qa[ks];
            #pragma unroll
            for (int n = 0; n < 4; ++n) {
                short8v bb = *(const short8v*)&Ks[(n * 16 + lr) * HP2 + ks * 32 + hi * 8];
                s4[n] = __builtin_amdgcn_mfma_f32_16x16x32_bf16(a, bb, s4[n], 0, 0, 0);
            }
        }

        const bool partial = (kt * 64 + 63 > qrow_g);
        if (partial) {
            #pragma unroll
            for (int n = 0; n < 4; ++n) {
                int kcol = kt * 64 + n * 16 + lr;
                #pragma unroll
                for (int reg = 0; reg < 4; ++reg) {
                    float y = s4[n][reg] * SCL;
                    s4[n][reg] = (kcol <= mrow0 + reg) ? y : -INFINITY;
                }
            }
        } else {
            #pragma unroll
            for (int n = 0; n < 4; ++n)
                #pragma unroll
                for (int reg = 0; reg < 4; ++reg) s4[n][reg] *= SCL;
        }

        #pragma unroll
        for (int reg = 0; reg < 4; ++reg) {
            float mx = fmaxf(fmaxf(s4[0][reg], s4[1][reg]),
                             fmaxf(s4[2][reg], s4[3][reg]));
            mx = fmaxf(mx, __shfl_xor(mx, 1));
            mx = fmaxf(mx, __shfl_xor(mx, 2));
            mx = fmaxf(mx, __shfl_xor(mx, 4));
            mx = fmaxf(mx, __shfl_xor(mx, 8));
            float mN = fmaxf(m[reg], mx);
            float sc = exp2f(m[reg] - mN);
            float ps = 0.f;
            #pragma unroll
            for (int n = 0; n < 4; ++n) {
                float p = exp2f(s4[n][reg] - mN);
                s4[n][reg] = p;
                ps += p;
            }
            ps += __shfl_xor(ps, 1);
            ps += __shfl_xor(ps, 2);
            ps += __shfl_xor(ps, 4);
            ps += __shfl_xor(ps, 8);
            l[reg] = l[reg] * sc + ps;
            m[reg] = mN;
            #pragma unroll
            for (int n = 0; n < 4; ++n) o[n][reg] *= sc;
        }

        #pragma unroll
        for (int n = 0; n < 4; ++n)
            #pragma unroll
            for (int reg = 0; reg < 4; ++reg)
                Pl[wv][(hi * 4 + reg) * HP2 + n * 16 + lr] = f2bf(s4[n][reg]);

        #pragma unroll
        for (int ks = 0; ks < 2; ++ks) {
            short8v a = *(const short8v*)&Pl[wv][lr * HP2 + ks * 32 + hi * 8];
            #pragma unroll
            for (int n = 0; n < 4; ++n) {
                short8v bb = *(const short8v*)&Vt[(n * 16 + lr) * HP2 + ks * 32 + hi * 8];
                o[n] = __builtin_amdgcn_mfma_f32_16x16x32_bf16(a, bb, o[n], 0, 0, 0);
            }
        }
    }

    #pragma unroll
    for (int reg = 0; reg < 4; ++reg) {
        float inv = 1.0f / l[reg];
        float* orow = out + base + (long)(mrow0 + reg) * Hn;
        #pragma unroll
        for (int n = 0; n < 4; ++n)
            orow[n * 16 + lr] = o[n][reg] * inv;
    }
}

extern "C" void kernel_launch(void* const* d_in, const int* in_sizes, int n_in,
                              void* d_out, int out_size, void* d_ws, size_t ws_size,
                              hipStream_t stream) {
    const float* x  = (const float*)d_in[0];
    const float* Wq = (const float*)d_in[1];
    const float* Wk = (const float*)d_in[2];
    const float* Wv = (const float*)d_in[3];
    float* out = (float*)d_out;

    const size_t n = (size_t)Bn * Tn * Hn;   // 4.19M elements per tensor
    float*  qws = (float*)d_ws;              // fp32, 16.8 MB
    float*  kws = qws + n;                   // fp32, 16.8 MB
    ushort* vTs = (ushort*)(kws + n);        // bf16 [b][h][t], 8.4 MB
    ushort* wcT = vTs + n;                   // bf16 W, 96 KB

    prep_w_kernel<<<dim3(NQKV), 256, 0, stream>>>(Wq, Wk, Wv, wcT);
    qkv_mfma_kernel<1><<<dim3(Bn * Tn / 64), 256, 0, stream>>>(x, wcT, qws, kws, vTs);
    // ---- ablation dispatch: same staging+MFMA, zero stores (diagnostic) ----
    qkv_mfma_kernel<0><<<dim3(Bn * Tn / 64), 256, 0, stream>>>(x, wcT, qws, kws, vTs);
    attn_mfma_kernel<<<dim3(512), 512, 0, stream>>>(qws, kws, vTs, out);
}

// Round 12
// 57.040 us; speedup vs baseline: 1.4191x; 1.4191x over previous
//
#include <hip/hip_runtime.h>
#include <hip/hip_bf16.h>
#include <math.h>

#define Bn 128
#define Tn 512
#define Cn 256
#define Hn 64
#define NQKV 192
#define XP 264          // padded bf16 LDS stride for x tile (528 B rows)
#define HP2 72          // padded bf16 LDS stride for attn tiles (144 B)
#define SCL 0.18033688011112042f   // log2(e)/8 : exp2-domain softmax scale

typedef __attribute__((ext_vector_type(8))) short short8v;   // 8 bf16
typedef __attribute__((ext_vector_type(4))) float float4v;   // MFMA C/D

__device__ __forceinline__ ushort f2bf(float f) {
    __hip_bfloat16 h = __float2bfloat16(f);   // RNE
    return *reinterpret_cast<ushort*>(&h);
}

// ---------------------------------------------------------------------------
// Prep: WcT[col][c] = W_m[c][h] as bf16, PRE-SWIZZLED within each 512 B row
// (ushort idx c ^ ((col&7)<<3)) so a linear global_load_lds copy lands
// XOR-swizzled in LDS (m173 pattern; fragment reads use matching XOR).
// ---------------------------------------------------------------------------
__global__ __launch_bounds__(256) void prep_w_kernel(
    const float* __restrict__ Wq, const float* __restrict__ Wk,
    const float* __restrict__ Wv, ushort* __restrict__ wcT)
{
    const int col = blockIdx.x;          // 0..191
    const int c   = threadIdx.x;         // 0..255
    const float* W = (col < 64) ? Wq : (col < 128) ? Wk : Wv;
    const int h = col & 63;
    wcT[col * Cn + (c ^ ((col & 7) << 3))] = f2bf(W[c * Hn + h]);
}

// ---------------------------------------------------------------------------
// QKV GEMM v7: 1024 blocks x 512 thr (8 waves), 64-row tile, ~145 KB LDS.
// W (96 KB) staged via global_load_lds (pre-swizzled src -> swizzled LDS,
// zero VGPR landing, overlaps x staging). x reg-staged fp32->bf16 (8 fl4/
// thread). Wave (s=wv&3 rows s*16, hh=wv>>2): q|k via SWAPPED-operand MFMA
// (D transposed: 4 consecutive h per lane) -> per-wave 2KB XOR bounce (no
// barrier) -> full-128B-line uint4 stores. v via normal order -> direct
// ushort4 stores to vT[b][h][t]. 1 barrier total; 8 store instrs/thread.
// ---------------------------------------------------------------------------
__global__ __launch_bounds__(512) void qkv_mfma_kernel(
    const float* __restrict__ x, const ushort* __restrict__ wcT,
    ushort* __restrict__ q, ushort* __restrict__ k, ushort* __restrict__ vT)
{
    __shared__ char lds[148480];
    // [0, 98304)        : W, 192 rows x 512 B, row-XOR-swizzled
    // [98304, 132096)   : x tile, 64 rows x 528 B (XP pad)
    // [132096, 148480)  : 8 x 2048 B per-wave q/k bounce
    const int XOFF = 98304;
    const int BOFF = 132096;

    const int tid  = threadIdx.x;
    const int lane = tid & 63;
    const int wv   = tid >> 6;             // 0..7
    const int lr   = lane & 15;
    const int hi   = lane >> 4;
    const int s    = wv & 3;               // 16-row strip
    const int hh   = wv >> 2;              // 0: q-cols, 1: k-cols (and v split)
    const long row0 = (long)blockIdx.x * 64;

    // ---- W: 96 KB via global_load_lds, 12 instrs/wave, fire-and-forget ----
    {
        const char* gw = (const char*)wcT;
        #pragma unroll
        for (int i = 0; i < 12; ++i) {
            int off = (wv * 12 + i) * 1024;
            __builtin_amdgcn_global_load_lds(
                (const __attribute__((address_space(1))) unsigned int*)(gw + off + (lane << 4)),
                (__attribute__((address_space(3))) unsigned int*)(lds + off),
                16, 0, 0);
        }
    }

    // ---- x: 8 float4/thread -> cvt -> padded ds_write ----
    {
        const float4* x4 = (const float4*)(x + row0 * Cn);
        float4 xr[8];
        #pragma unroll
        for (int i = 0; i < 8; ++i) xr[i] = x4[tid + i * 512];
        #pragma unroll
        for (int i = 0; i < 8; ++i) {
            int idx = tid + i * 512;           // 0..4095 uint2 slots
            int r   = idx >> 6;                // 0..63
            int c4  = idx & 63;
            union { ushort u[4]; uint2 p; } pk;
            pk.u[0] = f2bf(xr[i].x); pk.u[1] = f2bf(xr[i].y);
            pk.u[2] = f2bf(xr[i].z); pk.u[3] = f2bf(xr[i].w);
            *(uint2*)(lds + XOFF + r * 528 + c4 * 8) = pk.p;
        }
    }
    __syncthreads();   // drains W DMA (vmcnt) + x ds_writes

    // ---- MFMA: per wave 4 swapped q|k frags + 2 normal v frags, 8 ks ----
    float4v aqk[4], av[2];
    #pragma unroll
    for (int j = 0; j < 4; ++j) aqk[j] = (float4v){0.f, 0.f, 0.f, 0.f};
    av[0] = (float4v){0.f, 0.f, 0.f, 0.f};
    av[1] = av[0];

    const char* xrow = lds + XOFF + (s * 16 + lr) * 528 + hi * 16;
    const int wxor = (lr & 7) << 4;
    #pragma unroll
    for (int ks = 0; ks < 8; ++ks) {
        const int kb = (ks * 64 + hi * 16);
        short8v xa = *(const short8v*)(xrow + ks * 64);
        #pragma unroll
        for (int j = 0; j < 4; ++j) {
            short8v wf = *(const short8v*)(lds + (hh * 64 + j * 16 + lr) * 512 + (kb ^ wxor));
            aqk[j] = __builtin_amdgcn_mfma_f32_16x16x32_bf16(wf, xa, aqk[j], 0, 0, 0);  // swapped
        }
        #pragma unroll
        for (int j = 0; j < 2; ++j) {
            short8v wf = *(const short8v*)(lds + (128 + hh * 32 + j * 16 + lr) * 512 + (kb ^ wxor));
            av[j] = __builtin_amdgcn_mfma_f32_16x16x32_bf16(xa, wf, av[j], 0, 0, 0);    // normal
        }
    }

    // ---- vT: direct ushort4 stores (D rows = 4 consecutive t, fixed h) ----
    {
        const int bb = (int)(row0 >> 9);
        const int tl = (int)(row0 & 511) + s * 16 + hi * 4;
        #pragma unroll
        for (int j = 0; j < 2; ++j) {
            int h = hh * 32 + j * 16 + lr;
            ushort4 pk;
            pk.x = f2bf(av[j][0]); pk.y = f2bf(av[j][1]);
            pk.z = f2bf(av[j][2]); pk.w = f2bf(av[j][3]);
            *(ushort4*)(vT + ((long)bb * Hn + h) * Tn + tl) = pk;
        }
    }

    // ---- q|k: swapped D (4 consecutive h, fixed t=s*16+lr) -> wave bounce ----
    {
        char* bnc = lds + BOFF + wv * 2048;    // [16 t][64 h] ushort, XOR-swz
        #pragma unroll
        for (int j = 0; j < 4; ++j) {
            ushort4 pk;
            pk.x = f2bf(aqk[j][0]); pk.y = f2bf(aqk[j][1]);
            pk.z = f2bf(aqk[j][2]); pk.w = f2bf(aqk[j][3]);
            *(ushort4*)(bnc + lr * 128 + ((j * 32 + hi * 8) ^ ((lr & 7) << 4))) = pk;
        }
        // read back rows (intra-wave; compiler inserts lgkmcnt) + line stores
        ushort* dst = hh ? k : q;
        #pragma unroll
        for (int i = 0; i < 2; ++i) {
            int t = i * 8 + (lane >> 3);
            int c = lane & 7;
            uint4 w = *(const uint4*)(bnc + t * 128 + ((c * 16) ^ ((t & 7) << 4)));
            *(uint4*)(dst + (row0 + s * 16 + t) * Hn + c * 8) = w;
        }
    }
}

// ---------------------------------------------------------------------------
// MFMA flash attention, 128-row Q tile, 8 waves (512 thr). bf16 q/k/vT
// inputs (r4-r9 structure, known-good).
// ---------------------------------------------------------------------------
__global__ __launch_bounds__(512) void attn_mfma_kernel(
    const ushort* __restrict__ q, const ushort* __restrict__ k,
    const ushort* __restrict__ vT, float* __restrict__ out)
{
    __shared__ ushort Ks[64 * HP2];        // [key s][h]
    __shared__ ushort Vt[64 * HP2];        // [h][key s]
    __shared__ ushort Pl[8][16 * HP2];     // per-wave P rows

    const int tid = threadIdx.x;
    const int f   = blockIdx.x;            // 0..511
    const int c   = f & 255;
    const int b   = c >> 1;
    const int par = c & 1;
    const int qtp = (f < 256) ? par : (3 - par);   // q-tile 0..3
    const int ntiles = 2 * qtp + 2;

    const long base  = (long)b * Tn * Hn;
    const int lane = tid & 63;
    const int wv   = tid >> 6;             // 0..7
    const int lr   = lane & 15;
    const int hi   = lane >> 4;

    const int qrow_g = qtp * 128 + wv * 16;
    const int mrow0  = qrow_g + hi * 4;

    short8v qa[2];
    {
        const ushort* qp = q + base + (long)(qrow_g + lr) * Hn + hi * 8;
        qa[0] = *(const short8v*)(qp);
        qa[1] = *(const short8v*)(qp + 32);
    }

    const int sr  = tid >> 3;
    const int sc8 = tid & 7;
    uint4 kreg = *(const uint4*)(k + base + (long)sr * Hn + sc8 * 8);
    uint4 vreg = *(const uint4*)(vT + base + (long)sr * Tn + sc8 * 8);

    float4v o[4];
    #pragma unroll
    for (int n = 0; n < 4; ++n) o[n] = (float4v){0.f, 0.f, 0.f, 0.f};
    float m[4], l[4];
    #pragma unroll
    for (int reg = 0; reg < 4; ++reg) { m[reg] = -INFINITY; l[reg] = 0.f; }

    for (int kt = 0; kt < ntiles; ++kt) {
        __syncthreads();
        *(uint4*)&Ks[sr * HP2 + sc8 * 8] = kreg;
        *(uint4*)&Vt[sr * HP2 + sc8 * 8] = vreg;
        __syncthreads();
        if (kt + 1 < ntiles) {
            kreg = *(const uint4*)(k  + base + (long)((kt + 1) * 64 + sr) * Hn + sc8 * 8);
            vreg = *(const uint4*)(vT + base + (long)sr * Tn + (kt + 1) * 64 + sc8 * 8);
        }
        if (kt * 64 > qrow_g + 15) continue;

        float4v s4[4];
        #pragma unroll
        for (int n = 0; n < 4; ++n) s4[n] = (float4v){0.f, 0.f, 0.f, 0.f};
        #pragma unroll
        for (int ks = 0; ks < 2; ++ks) {
            short8v a = qa[ks];
            #pragma unroll
            for (int n = 0; n < 4; ++n) {
                short8v bb = *(const short8v*)&Ks[(n * 16 + lr) * HP2 + ks * 32 + hi * 8];
                s4[n] = __builtin_amdgcn_mfma_f32_16x16x32_bf16(a, bb, s4[n], 0, 0, 0);
            }
        }

        const bool partial = (kt * 64 + 63 > qrow_g);
        if (partial) {
            #pragma unroll
            for (int n = 0; n < 4; ++n) {
                int kcol = kt * 64 + n * 16 + lr;
                #pragma unroll
                for (int reg = 0; reg < 4; ++reg) {
                    float y = s4[n][reg] * SCL;
                    s4[n][reg] = (kcol <= mrow0 + reg) ? y : -INFINITY;
                }
            }
        } else {
            #pragma unroll
            for (int n = 0; n < 4; ++n)
                #pragma unroll
                for (int reg = 0; reg < 4; ++reg) s4[n][reg] *= SCL;
        }

        #pragma unroll
        for (int reg = 0; reg < 4; ++reg) {
            float mx = fmaxf(fmaxf(s4[0][reg], s4[1][reg]),
                             fmaxf(s4[2][reg], s4[3][reg]));
            mx = fmaxf(mx, __shfl_xor(mx, 1));
            mx = fmaxf(mx, __shfl_xor(mx, 2));
            mx = fmaxf(mx, __shfl_xor(mx, 4));
            mx = fmaxf(mx, __shfl_xor(mx, 8));
            float mN = fmaxf(m[reg], mx);
            float sc = exp2f(m[reg] - mN);
            float ps = 0.f;
            #pragma unroll
            for (int n = 0; n < 4; ++n) {
                float p = exp2f(s4[n][reg] - mN);
                s4[n][reg] = p;
                ps += p;
            }
            ps += __shfl_xor(ps, 1);
            ps += __shfl_xor(ps, 2);
            ps += __shfl_xor(ps, 4);
            ps += __shfl_xor(ps, 8);
            l[reg] = l[reg] * sc + ps;
            m[reg] = mN;
            #pragma unroll
            for (int n = 0; n < 4; ++n) o[n][reg] *= sc;
        }

        #pragma unroll
        for (int n = 0; n < 4; ++n)
            #pragma unroll
            for (int reg = 0; reg < 4; ++reg)
                Pl[wv][(hi * 4 + reg) * HP2 + n * 16 + lr] = f2bf(s4[n][reg]);

        #pragma unroll
        for (int ks = 0; ks < 2; ++ks) {
            short8v a = *(const short8v*)&Pl[wv][lr * HP2 + ks * 32 + hi * 8];
            #pragma unroll
            for (int n = 0; n < 4; ++n) {
                short8v bb = *(const short8v*)&Vt[(n * 16 + lr) * HP2 + ks * 32 + hi * 8];
                o[n] = __builtin_amdgcn_mfma_f32_16x16x32_bf16(a, bb, o[n], 0, 0, 0);
            }
        }
    }

    #pragma unroll
    for (int reg = 0; reg < 4; ++reg) {
        float inv = 1.0f / l[reg];
        float* orow = out + base + (long)(mrow0 + reg) * Hn;
        #pragma unroll
        for (int n = 0; n < 4; ++n)
            orow[n * 16 + lr] = o[n][reg] * inv;
    }
}

extern "C" void kernel_launch(void* const* d_in, const int* in_sizes, int n_in,
                              void* d_out, int out_size, void* d_ws, size_t ws_size,
                              hipStream_t stream) {
    const float* x  = (const float*)d_in[0];
    const float* Wq = (const float*)d_in[1];
    const float* Wk = (const float*)d_in[2];
    const float* Wv = (const float*)d_in[3];
    float* out = (float*)d_out;

    const size_t n = (size_t)Bn * Tn * Hn;
    ushort* qws = (ushort*)d_ws;
    ushort* kws = qws + n;
    ushort* vTs = kws + n;
    ushort* wcT = vTs + n;      // pre-swizzled bf16 W, 96 KB

    prep_w_kernel<<<dim3(NQKV), 256, 0, stream>>>(Wq, Wk, Wv, wcT);
    qkv_mfma_kernel<<<dim3(Bn * Tn / 64), 512, 0, stream>>>(x, wcT, qws, kws, vTs);
    attn_mfma_kernel<<<dim3(512), 512, 0, stream>>>(qws, kws, vTs, out);
}

// Round 13
// 51.456 us; speedup vs baseline: 1.5731x; 1.1085x over previous
//
#include <hip/hip_runtime.h>
#include <hip/hip_bf16.h>
#include <math.h>

#define Bn 128
#define Tn 512
#define Cn 256
#define Hn 64
#define HP2 72          // padded bf16 LDS stride for attn tiles (144 B)
#define SCL 0.18033688011112042f   // log2(e)/8 : exp2-domain softmax scale

typedef __attribute__((ext_vector_type(8))) short short8v;   // 8 bf16
typedef __attribute__((ext_vector_type(4))) float float4v;   // MFMA C/D

__device__ __forceinline__ ushort f2bf(float f) {
    __hip_bfloat16 h = __float2bfloat16(f);   // RNE
    return *reinterpret_cast<ushort*>(&h);
}

// ---------------------------------------------------------------------------
// Prep: wcT2 = W columns regrouped for the nh-split kernel, bf16,
// PRE-SWIZZLED within each 512 B row (key = LDS row rr = row%96) so a linear
// global_load_lds lands XOR-swizzled (m173). Row order:
//   nh=0: [ q h0..63 | v h0..31 ]   nh=1: [ k h0..63 | v h32..63 ]
// ---------------------------------------------------------------------------
__global__ __launch_bounds__(256) void prep_w_kernel(
    const float* __restrict__ Wq, const float* __restrict__ Wk,
    const float* __restrict__ Wv, ushort* __restrict__ wcT2)
{
    const int row = blockIdx.x;          // 0..191
    const int c   = threadIdx.x;         // 0..255
    const int nh  = row / 96;
    const int rr  = row % 96;
    const int scol = (nh == 0) ? (rr < 64 ? rr : 128 + (rr - 64))
                               : (rr < 64 ? 64 + rr : 160 + (rr - 64));
    const float* W = (scol < 64) ? Wq : (scol < 128) ? Wk : Wv;
    const int h = scol & 63;
    wcT2[row * Cn + (c ^ ((rr & 7) << 3))] = f2bf(W[c * Hn + h]);
}

// ---------------------------------------------------------------------------
// QKV GEMM v8 = r8 skeleton + r12 epilogue.
// 2048 blocks x 256 thr (4 waves). LDS exactly 80 KB -> 2 blocks/CU.
// Block = 64 rows x 96 cols (nh half); halves of a row-tile adjacent in
// dispatch (bid&8) -> same XCD -> 2nd x read L2-hot. W-half (48 KB) via
// global_load_lds (pre-swizzled src). Wave = one 16-row strip x all 96
// cols: frags 0..3 = q|k via SWAPPED mfma(W,x) (D: 4 consecutive h per
// lane), frags 4..5 = v via normal mfma(x,W) (D: 4 consecutive t) ->
// direct ushort4 to vT. q|k retire through per-wave 2 KB XOR bounce ->
// 2 full-128B-line uint4 stores. 4 store instrs/thread.
// ---------------------------------------------------------------------------
__global__ __launch_bounds__(256) void qkv_mfma_kernel(
    const float* __restrict__ x, const ushort* __restrict__ wcT2,
    ushort* __restrict__ q, ushort* __restrict__ k, ushort* __restrict__ vT)
{
    __shared__ char lds[81920];
    // [0, 49152)     : W-half, 96 rows x 512 B, row-XOR-swizzled
    // [49152, 81920) : x tile, 64 rows x 512 B, row-XOR-swizzled;
    //                  first 8 KB reused as 4 x 2 KB per-wave q/k bounce
    const int XOFF = 49152;

    const int tid  = threadIdx.x;
    const int lane = tid & 63;
    const int wv   = tid >> 6;             // 0..3 : 16-row strip
    const int lr   = lane & 15;
    const int hi   = lane >> 4;

    const int bid     = blockIdx.x;
    const int nh      = (bid >> 3) & 1;                   // function half
    const int rowtile = (bid & 7) | ((bid >> 4) << 3);    // 0..1023
    const long rows0  = (long)rowtile * 64;

    // ---- W-half: 48 KB via global_load_lds, fire-and-forget ----
    {
        const char* gw = (const char*)wcT2 + (long)nh * 96 * 512;
        #pragma unroll
        for (int i = 0; i < 12; ++i) {
            int off = (wv * 12 + i) * 1024;
            __builtin_amdgcn_global_load_lds(
                (const __attribute__((address_space(1))) unsigned int*)(gw + off + (lane << 4)),
                (__attribute__((address_space(3))) unsigned int*)(lds + off),
                16, 0, 0);
        }
    }

    // ---- x tile: 16 float4/thread -> cvt -> swizzled ds_write ----
    {
        const float4* x4 = (const float4*)(x + rows0 * Cn);
        float4 xr[16];
        #pragma unroll
        for (int i = 0; i < 16; ++i) xr[i] = x4[tid + i * 256];
        #pragma unroll
        for (int i = 0; i < 16; ++i) {
            int idx = tid + i * 256;           // 0..4095 uint2 slots
            int r   = idx >> 6;                // 0..63
            int c4  = idx & 63;
            union { ushort u[4]; uint2 p; } pk;
            pk.u[0] = f2bf(xr[i].x); pk.u[1] = f2bf(xr[i].y);
            pk.u[2] = f2bf(xr[i].z); pk.u[3] = f2bf(xr[i].w);
            int off = (r * 512 + c4 * 8) ^ ((r & 7) << 4);
            *(uint2*)(lds + XOFF + off) = pk.p;
        }
    }
    __syncthreads();   // drains W DMA (vmcnt) + x ds_writes

    // ---- MFMA: per wave, per ks: 1 xa + 4 swapped (q|k) + 2 normal (v) ----
    float4v aqk[4], av[2];
    #pragma unroll
    for (int j = 0; j < 4; ++j) aqk[j] = (float4v){0.f, 0.f, 0.f, 0.f};
    av[0] = (float4v){0.f, 0.f, 0.f, 0.f};
    av[1] = av[0];

    const int xrow = wv * 16 + lr;
    const int xxor = (lr & 7) << 4;
    #pragma unroll
    for (int ks = 0; ks < 8; ++ks) {
        const int kb = ks * 64 + hi * 16;
        short8v xa = *(const short8v*)(lds + XOFF + ((xrow * 512 + kb) ^ xxor));
        #pragma unroll
        for (int j = 0; j < 4; ++j) {
            short8v wf = *(const short8v*)(lds + (j * 16 + lr) * 512 + (kb ^ xxor));
            aqk[j] = __builtin_amdgcn_mfma_f32_16x16x32_bf16(wf, xa, aqk[j], 0, 0, 0); // swapped
        }
        #pragma unroll
        for (int j = 0; j < 2; ++j) {
            short8v wf = *(const short8v*)(lds + (64 + j * 16 + lr) * 512 + (kb ^ xxor));
            av[j] = __builtin_amdgcn_mfma_f32_16x16x32_bf16(xa, wf, av[j], 0, 0, 0);   // normal
        }
    }

    // ---- v: direct ushort4 stores (D = 4 consecutive t at fixed h) ----
    {
        const int bb = (int)(rows0 >> 9);
        const int tl = (int)(rows0 & 511) + wv * 16 + hi * 4;
        #pragma unroll
        for (int j = 0; j < 2; ++j) {
            int h = nh * 32 + j * 16 + lr;
            ushort4 pk;
            pk.x = f2bf(av[j][0]); pk.y = f2bf(av[j][1]);
            pk.z = f2bf(av[j][2]); pk.w = f2bf(av[j][3]);
            *(ushort4*)(vT + ((long)bb * Hn + h) * Tn + tl) = pk;
        }
    }

    __syncthreads();   // x tile fully consumed -> reuse head as bounce

    // ---- q|k: swapped D (4 consecutive h at fixed t) -> per-wave bounce ----
    {
        char* bnc = lds + XOFF + wv * 2048;    // [16 t][64 h] ushort, XOR-swz
        #pragma unroll
        for (int j = 0; j < 4; ++j) {
            ushort4 pk;
            pk.x = f2bf(aqk[j][0]); pk.y = f2bf(aqk[j][1]);
            pk.z = f2bf(aqk[j][2]); pk.w = f2bf(aqk[j][3]);
            *(ushort4*)(bnc + lr * 128 + ((j * 32 + hi * 8) ^ ((lr & 7) << 4))) = pk;
        }
        ushort* dst = nh ? k : q;
        #pragma unroll
        for (int i = 0; i < 2; ++i) {
            int t = i * 8 + (lane >> 3);
            int c = lane & 7;
            uint4 w = *(const uint4*)(bnc + t * 128 + ((c * 16) ^ ((t & 7) << 4)));
            *(uint4*)(dst + (rows0 + wv * 16 + t) * Hn + c * 8) = w;
        }
    }
}

// ---------------------------------------------------------------------------
// MFMA flash attention, 128-row Q tile, 8 waves (512 thr). Unchanged (r12).
// ---------------------------------------------------------------------------
__global__ __launch_bounds__(512) void attn_mfma_kernel(
    const ushort* __restrict__ q, const ushort* __restrict__ k,
    const ushort* __restrict__ vT, float* __restrict__ out)
{
    __shared__ ushort Ks[64 * HP2];        // [key s][h]
    __shared__ ushort Vt[64 * HP2];        // [h][key s]
    __shared__ ushort Pl[8][16 * HP2];     // per-wave P rows

    const int tid = threadIdx.x;
    const int f   = blockIdx.x;            // 0..511
    const int c   = f & 255;
    const int b   = c >> 1;
    const int par = c & 1;
    const int qtp = (f < 256) ? par : (3 - par);   // q-tile 0..3
    const int ntiles = 2 * qtp + 2;

    const long base  = (long)b * Tn * Hn;
    const int lane = tid & 63;
    const int wv   = tid >> 6;             // 0..7
    const int lr   = lane & 15;
    const int hi   = lane >> 4;

    const int qrow_g = qtp * 128 + wv * 16;
    const int mrow0  = qrow_g + hi * 4;

    short8v qa[2];
    {
        const ushort* qp = q + base + (long)(qrow_g + lr) * Hn + hi * 8;
        qa[0] = *(const short8v*)(qp);
        qa[1] = *(const short8v*)(qp + 32);
    }

    const int sr  = tid >> 3;
    const int sc8 = tid & 7;
    uint4 kreg = *(const uint4*)(k + base + (long)sr * Hn + sc8 * 8);
    uint4 vreg = *(const uint4*)(vT + base + (long)sr * Tn + sc8 * 8);

    float4v o[4];
    #pragma unroll
    for (int n = 0; n < 4; ++n) o[n] = (float4v){0.f, 0.f, 0.f, 0.f};
    float m[4], l[4];
    #pragma unroll
    for (int reg = 0; reg < 4; ++reg) { m[reg] = -INFINITY; l[reg] = 0.f; }

    for (int kt = 0; kt < ntiles; ++kt) {
        __syncthreads();
        *(uint4*)&Ks[sr * HP2 + sc8 * 8] = kreg;
        *(uint4*)&Vt[sr * HP2 + sc8 * 8] = vreg;
        __syncthreads();
        if (kt + 1 < ntiles) {
            kreg = *(const uint4*)(k  + base + (long)((kt + 1) * 64 + sr) * Hn + sc8 * 8);
            vreg = *(const uint4*)(vT + base + (long)sr * Tn + (kt + 1) * 64 + sc8 * 8);
        }
        if (kt * 64 > qrow_g + 15) continue;

        float4v s4[4];
        #pragma unroll
        for (int n = 0; n < 4; ++n) s4[n] = (float4v){0.f, 0.f, 0.f, 0.f};
        #pragma unroll
        for (int ks = 0; ks < 2; ++ks) {
            short8v a = qa[ks];
            #pragma unroll
            for (int n = 0; n < 4; ++n) {
                short8v bb = *(const short8v*)&Ks[(n * 16 + lr) * HP2 + ks * 32 + hi * 8];
                s4[n] = __builtin_amdgcn_mfma_f32_16x16x32_bf16(a, bb, s4[n], 0, 0, 0);
            }
        }

        const bool partial = (kt * 64 + 63 > qrow_g);
        if (partial) {
            #pragma unroll
            for (int n = 0; n < 4; ++n) {
                int kcol = kt * 64 + n * 16 + lr;
                #pragma unroll
                for (int reg = 0; reg < 4; ++reg) {
                    float y = s4[n][reg] * SCL;
                    s4[n][reg] = (kcol <= mrow0 + reg) ? y : -INFINITY;
                }
            }
        } else {
            #pragma unroll
            for (int n = 0; n < 4; ++n)
                #pragma unroll
                for (int reg = 0; reg < 4; ++reg) s4[n][reg] *= SCL;
        }

        #pragma unroll
        for (int reg = 0; reg < 4; ++reg) {
            float mx = fmaxf(fmaxf(s4[0][reg], s4[1][reg]),
                             fmaxf(s4[2][reg], s4[3][reg]));
            mx = fmaxf(mx, __shfl_xor(mx, 1));
            mx = fmaxf(mx, __shfl_xor(mx, 2));
            mx = fmaxf(mx, __shfl_xor(mx, 4));
            mx = fmaxf(mx, __shfl_xor(mx, 8));
            float mN = fmaxf(m[reg], mx);
            float sc = exp2f(m[reg] - mN);
            float ps = 0.f;
            #pragma unroll
            for (int n = 0; n < 4; ++n) {
                float p = exp2f(s4[n][reg] - mN);
                s4[n][reg] = p;
                ps += p;
            }
            ps += __shfl_xor(ps, 1);
            ps += __shfl_xor(ps, 2);
            ps += __shfl_xor(ps, 4);
            ps += __shfl_xor(ps, 8);
            l[reg] = l[reg] * sc + ps;
            m[reg] = mN;
            #pragma unroll
            for (int n = 0; n < 4; ++n) o[n][reg] *= sc;
        }

        #pragma unroll
        for (int n = 0; n < 4; ++n)
            #pragma unroll
            for (int reg = 0; reg < 4; ++reg)
                Pl[wv][(hi * 4 + reg) * HP2 + n * 16 + lr] = f2bf(s4[n][reg]);

        #pragma unroll
        for (int ks = 0; ks < 2; ++ks) {
            short8v a = *(const short8v*)&Pl[wv][lr * HP2 + ks * 32 + hi * 8];
            #pragma unroll
            for (int n = 0; n < 4; ++n) {
                short8v bb = *(const short8v*)&Vt[(n * 16 + lr) * HP2 + ks * 32 + hi * 8];
                o[n] = __builtin_amdgcn_mfma_f32_16x16x32_bf16(a, bb, o[n], 0, 0, 0);
            }
        }
    }

    #pragma unroll
    for (int reg = 0; reg < 4; ++reg) {
        float inv = 1.0f / l[reg];
        float* orow = out + base + (long)(mrow0 + reg) * Hn;
        #pragma unroll
        for (int n = 0; n < 4; ++n)
            orow[n * 16 + lr] = o[n][reg] * inv;
    }
}

extern "C" void kernel_launch(void* const* d_in, const int* in_sizes, int n_in,
                              void* d_out, int out_size, void* d_ws, size_t ws_size,
                              hipStream_t stream) {
    const float* x  = (const float*)d_in[0];
    const float* Wq = (const float*)d_in[1];
    const float* Wk = (const float*)d_in[2];
    const float* Wv = (const float*)d_in[3];
    float* out = (float*)d_out;

    const size_t n = (size_t)Bn * Tn * Hn;
    ushort* qws  = (ushort*)d_ws;
    ushort* kws  = qws + n;
    ushort* vTs  = kws + n;
    ushort* wcT2 = vTs + n;      // regrouped pre-swizzled bf16 W, 96 KB

    prep_w_kernel<<<dim3(192), 256, 0, stream>>>(Wq, Wk, Wv, wcT2);
    qkv_mfma_kernel<<<dim3(2048), 256, 0, stream>>>(x, wcT2, qws, kws, vTs);
    attn_mfma_kernel<<<dim3(512), 512, 0, stream>>>(qws, kws, vTs, out);
}